// Round 2
// baseline (462.119 us; speedup 1.0000x reference)
//
#include <hip/hip_runtime.h>
#include <hip/hip_cooperative_groups.h>
#include <math.h>

namespace cg = cooperative_groups;

#define BB 32
#define HH 56
#define WW 56
#define NPIX (BB * HH * WW)        // 100352 pixels, 256 fp32 channels each
#define NBLK 1024                  // 4 blocks/CU on 256 CUs -> all co-resident
#define NTHR 256
#define NWAVES (NBLK * NTHR / 64)  // 4096 waves

// Single cooperative kernel: pool -> grid.sync -> conv+sigmoid -> grid.sync -> scale.
// __launch_bounds__(256,4): 4 waves/EU => 4 blocks/CU => 1024 blocks co-resident.
__global__ __launch_bounds__(NTHR, 4) void fused_kernel(
    const float* __restrict__ x,
    const float* __restrict__ cw,     // [7,7,2,1] HWIO
    const float* __restrict__ cb,     // [1]
    float* __restrict__ out,
    float* __restrict__ pooled,       // ws: NPIX*2 floats (avg, max)
    float* __restrict__ attn)         // ws: NPIX floats
{
    cg::grid_group grid = cg::this_grid();
    const int tid  = blockIdx.x * NTHR + threadIdx.x;
    const int wave = tid >> 6;
    const int lane = threadIdx.x & 63;
    const float4* x4 = (const float4*)x;

    // ---- Phase 1: per-pixel channel mean+max. 4 pixels per wave iteration,
    // 4 independent shuffle chains for ILP. NPIX/4 = 25088 groups / 4096 waves.
    for (int pg = wave; pg < NPIX / 4; pg += NWAVES) {
        const int p0 = pg * 4;
        float s[4], m[4];
#pragma unroll
        for (int j = 0; j < 4; ++j) {
            float4 v = x4[(size_t)(p0 + j) * 64 + lane];
            s[j] = (v.x + v.y) + (v.z + v.w);
            m[j] = fmaxf(fmaxf(v.x, v.y), fmaxf(v.z, v.w));
        }
#pragma unroll
        for (int o = 32; o > 0; o >>= 1) {
#pragma unroll
            for (int j = 0; j < 4; ++j) {
                s[j] += __shfl_down(s[j], o, 64);
                m[j] = fmaxf(m[j], __shfl_down(m[j], o, 64));
            }
        }
        if (lane == 0) {
#pragma unroll
            for (int j = 0; j < 4; ++j) {
                pooled[(p0 + j) * 2]     = s[j] * (1.0f / 256.0f);
                pooled[(p0 + j) * 2 + 1] = m[j];
            }
        }
    }
    grid.sync();

    // ---- Phase 2: 7x7 SAME conv (2->1) + bias + sigmoid, one thread per pixel.
    // Pooled map is 0.8 MB -> L2-resident. 262144 threads >= NPIX: single pass.
    if (tid < NPIX) {
        const int idx = tid;
        const int b  = idx / (HH * WW);
        const int hw = idx % (HH * WW);
        const int h  = hw / WW;
        const int w  = hw % WW;
        float acc = cb[0];
        const float* base = pooled + (size_t)b * HH * WW * 2;
#pragma unroll
        for (int dh = 0; dh < 7; ++dh) {
            const int ih = h + dh - 3;
            if (ih < 0 || ih >= HH) continue;
#pragma unroll
            for (int dw = 0; dw < 7; ++dw) {
                const int iw = w + dw - 3;
                if (iw < 0 || iw >= WW) continue;
                const float* p = base + (ih * WW + iw) * 2;
                const float* k = cw + (dh * 7 + dw) * 2;
                acc = fmaf(p[0], k[0], acc);
                acc = fmaf(p[1], k[1], acc);
            }
        }
        attn[idx] = 1.0f / (1.0f + expf(-acc));
    }
    grid.sync();

    // ---- Phase 3: out = x * attn (broadcast over 256 ch). x re-read is L3-warm.
    const size_t n4 = (size_t)NPIX * 64;   // 64 float4s per pixel
    float4* o4 = (float4*)out;
    for (size_t i = tid; i < n4; i += (size_t)NBLK * NTHR) {
        const float a = attn[i >> 6];
        float4 v = x4[i];
        v.x *= a; v.y *= a; v.z *= a; v.w *= a;
        o4[i] = v;
    }
}

extern "C" void kernel_launch(void* const* d_in, const int* in_sizes, int n_in,
                              void* d_out, int out_size, void* d_ws, size_t ws_size,
                              hipStream_t stream) {
    const float* x  = (const float*)d_in[0];
    const float* cw = (const float*)d_in[1];
    const float* cb = (const float*)d_in[2];
    float* out = (float*)d_out;
    float* pooled = (float*)d_ws;
    float* attn   = pooled + (size_t)NPIX * 2;

    void* args[] = { (void*)&x, (void*)&cw, (void*)&cb,
                     (void*)&out, (void*)&pooled, (void*)&attn };
    hipLaunchCooperativeKernel((const void*)fused_kernel,
                               dim3(NBLK), dim3(NTHR), args, 0, stream);
}

// Round 3
// 202.688 us; speedup vs baseline: 2.2799x; 2.2799x over previous
//
#include <hip/hip_runtime.h>
#include <math.h>

#define BB 32
#define HH 56
#define WW 56
#define NPIX (BB * HH * WW)   // 100352 pixels, 256 fp32 channels each

typedef float vfloat4 __attribute__((ext_vector_type(4)));

// ---- Kernel 1: per-pixel channel mean+max.
// Grid-stride; each wave processes 4 pixels per iteration with 4 independent
// shuffle-reduction chains (ILP). 2048 blocks * 4 waves = 8192 waves.
#define POOL_BLOCKS 2048
#define POOL_WAVES (POOL_BLOCKS * 4)
__global__ __launch_bounds__(256) void pool_kernel(const float* __restrict__ x,
                                                   float* __restrict__ pooled) {
    const int wave = (blockIdx.x * 256 + threadIdx.x) >> 6;
    const int lane = threadIdx.x & 63;
    const vfloat4* x4 = (const vfloat4*)x;

    for (int pg = wave; pg < NPIX / 4; pg += POOL_WAVES) {
        const int p0 = pg * 4;
        float s[4], m[4];
#pragma unroll
        for (int j = 0; j < 4; ++j) {
            vfloat4 v = x4[(size_t)(p0 + j) * 64 + lane];
            s[j] = (v.x + v.y) + (v.z + v.w);
            m[j] = fmaxf(fmaxf(v.x, v.y), fmaxf(v.z, v.w));
        }
#pragma unroll
        for (int o = 32; o > 0; o >>= 1) {
#pragma unroll
            for (int j = 0; j < 4; ++j) {
                s[j] += __shfl_down(s[j], o, 64);
                m[j] = fmaxf(m[j], __shfl_down(m[j], o, 64));
            }
        }
        if (lane == 0) {
#pragma unroll
            for (int j = 0; j < 4; ++j) {
                pooled[(p0 + j) * 2]     = s[j] * (1.0f / 256.0f);
                pooled[(p0 + j) * 2 + 1] = m[j];
            }
        }
    }
}

// ---- Kernel 2: fused 7x7 conv + sigmoid + channel-broadcast scale.
// Each block (256 thr = 4 waves) owns 64 pixels. Wave 0 computes attn for the
// 64 pixels into LDS (pooled is L2-resident, halo reads cross block freely),
// then all 4 waves stream 64 KB of x (L3-warm) and write out non-temporally.
__global__ __launch_bounds__(256) void conv_scale_kernel(
    const float* __restrict__ x,
    const float* __restrict__ pooled,
    const float* __restrict__ cw,     // [7,7,2,1] HWIO
    const float* __restrict__ cb,     // [1]
    float* __restrict__ out) {
    __shared__ float attn_s[64];
    const int pix0 = blockIdx.x * 64;
    const int t = threadIdx.x;

    if (t < 64) {
        const int idx = pix0 + t;
        const int b  = idx / (HH * WW);
        const int hw = idx % (HH * WW);
        const int h  = hw / WW;
        const int w  = hw % WW;
        float acc = cb[0];
        const float* base = pooled + (size_t)b * HH * WW * 2;
#pragma unroll
        for (int dh = 0; dh < 7; ++dh) {
            const int ih = h + dh - 3;
            if (ih < 0 || ih >= HH) continue;
#pragma unroll
            for (int dw = 0; dw < 7; ++dw) {
                const int iw = w + dw - 3;
                if (iw < 0 || iw >= WW) continue;
                const float* p = base + (ih * WW + iw) * 2;
                const float* k = cw + (dh * 7 + dw) * 2;
                acc = fmaf(p[0], k[0], acc);
                acc = fmaf(p[1], k[1], acc);
            }
        }
        attn_s[t] = 1.0f / (1.0f + expf(-acc));
    }
    __syncthreads();

    const int wv = t >> 6;
    const int lane = t & 63;
    const vfloat4* x4 = (const vfloat4*)x;
    vfloat4* o4 = (vfloat4*)out;
#pragma unroll 4
    for (int j = 0; j < 16; ++j) {
        const int p = wv * 16 + j;                      // local pixel 0..63
        const size_t gi = (size_t)(pix0 + p) * 64 + lane;
        const float a = attn_s[p];
        vfloat4 v = x4[gi];
        v.x *= a; v.y *= a; v.z *= a; v.w *= a;
        __builtin_nontemporal_store(v, &o4[gi]);
    }
}

extern "C" void kernel_launch(void* const* d_in, const int* in_sizes, int n_in,
                              void* d_out, int out_size, void* d_ws, size_t ws_size,
                              hipStream_t stream) {
    const float* x  = (const float*)d_in[0];
    const float* cw = (const float*)d_in[1];
    const float* cb = (const float*)d_in[2];
    float* out = (float*)d_out;
    float* pooled = (float*)d_ws;      // NPIX*2 floats

    pool_kernel<<<POOL_BLOCKS, 256, 0, stream>>>(x, pooled);
    conv_scale_kernel<<<NPIX / 64, 256, 0, stream>>>(x, pooled, cw, cb, out);
}